// Round 15
// baseline (193.075 us; speedup 1.0000x reference)
//
#include <hip/hip_runtime.h>
#include <hip/hip_bf16.h>

typedef __attribute__((ext_vector_type(8))) __bf16 bf16x8;
typedef __attribute__((ext_vector_type(4))) float f32x4;
typedef __attribute__((ext_vector_type(4))) unsigned short u16x4;
typedef unsigned short u16;

#define AS3(p) ((__attribute__((address_space(3))) void*)(p))
#define AS1(p) ((const __attribute__((address_space(1))) void*)(p))

// 0.125 (1/sqrt(64)) * log2(e): folded into q at QKV-GEMM epilogue so the
// attention softmax can use exp2 directly with no per-element scaling.
#define QSCALE 0.18033688011112042f

__device__ __forceinline__ u16 f2b(float f) {
    __hip_bfloat16 h = __float2bfloat16(f);
    return __builtin_bit_cast(u16, h);
}

// Exact-enough GELU: Abramowitz-Stegun 7.1.26 erf (max abs err 1.5e-7)
__device__ __forceinline__ float gelu_exact(float v) {
    const float z = v * 0.70710678118654752f;
    const float a = fabsf(z);
    const float t = __builtin_amdgcn_rcpf(1.0f + 0.3275911f * a);
    float p = 1.061405429f;
    p = p * t - 1.453152027f;
    p = p * t + 1.421413741f;
    p = p * t - 0.284496736f;
    p = p * t + 0.254829592f;
    p = p * t;
    float erfv = 1.0f - p * __expf(-a * a);
    erfv = copysignf(erfv, z);
    return 0.5f * v * (1.0f + erfv);
}

// ---------------------------------------------------------------------------
// Weight transpose: W [K][N] fp32 -> WT [N][K] bf16 (tiled, padded LDS)
// ---------------------------------------------------------------------------
__global__ __launch_bounds__(256) void transpose_w(
    const float* __restrict__ W, u16* __restrict__ WT, int K, int N)
{
    __shared__ u16 tile[32][33];
    const int tx = threadIdx.x & 31, ty = threadIdx.x >> 5;
    const int n0 = blockIdx.x * 32, k0 = blockIdx.y * 32;
    #pragma unroll
    for (int p = 0; p < 4; ++p)
        tile[ty + p * 8][tx] = f2b(W[(size_t)(k0 + ty + p * 8) * N + n0 + tx]);
    __syncthreads();
    #pragma unroll
    for (int p = 0; p < 4; ++p)
        WT[(size_t)(n0 + ty + p * 8) * K + k0 + tx] = tile[tx][ty + p * 8];
}

// Fused Q/K/V/P weight transpose (one launch, z picks the matrix)
__global__ __launch_bounds__(256) void transpose_w4(
    const float* __restrict__ W0, const float* __restrict__ W1,
    const float* __restrict__ W2, const float* __restrict__ W3,
    u16* __restrict__ WTqkv, u16* __restrict__ WTp)
{
    __shared__ u16 tile[32][33];
    const int z = blockIdx.z;
    const float* W = (z == 0) ? W0 : (z == 1) ? W1 : (z == 2) ? W2 : W3;
    u16* dst = (z == 3) ? WTp : WTqkv + (size_t)z * 1024 * 1024;
    const int tx = threadIdx.x & 31, ty = threadIdx.x >> 5;
    const int n0 = blockIdx.x * 32, k0 = blockIdx.y * 32;
    #pragma unroll
    for (int p = 0; p < 4; ++p)
        tile[ty + p * 8][tx] = f2b(W[(size_t)(k0 + ty + p * 8) * 1024 + n0 + tx]);
    __syncthreads();
    #pragma unroll
    for (int p = 0; p < 4; ++p)
        dst[(size_t)(n0 + ty + p * 8) * 1024 + k0 + tx] = tile[tx][ty + p * 8];
}

// ---------------------------------------------------------------------------
// LayerNorm: x fp32 [rows][1024] -> y bf16, one block per row
// ---------------------------------------------------------------------------
__global__ __launch_bounds__(256) void ln_bf16(
    const float* __restrict__ xin, const float* __restrict__ gam,
    const float* __restrict__ bet, u16* __restrict__ yout)
{
    __shared__ float red[8];
    const int row = blockIdx.x, tid = threadIdx.x;
    float4 v = ((const float4*)(xin + (size_t)row * 1024))[tid];
    float s = v.x + v.y + v.z + v.w;
    #pragma unroll
    for (int o = 32; o > 0; o >>= 1) s += __shfl_xor(s, o, 64);
    if ((tid & 63) == 0) red[tid >> 6] = s;
    __syncthreads();
    const float mu = (red[0] + red[1] + red[2] + red[3]) * (1.f / 1024.f);
    const float dx = v.x - mu, dy = v.y - mu, dz = v.z - mu, dw = v.w - mu;
    float sq = dx * dx + dy * dy + dz * dz + dw * dw;
    #pragma unroll
    for (int o = 32; o > 0; o >>= 1) sq += __shfl_xor(sq, o, 64);
    if ((tid & 63) == 0) red[4 + (tid >> 6)] = sq;
    __syncthreads();
    const float var = (red[4] + red[5] + red[6] + red[7]) * (1.f / 1024.f);
    const float inv = rsqrtf(var + 1e-5f);
    const float4 G = ((const float4*)gam)[tid];
    const float4 Bt = ((const float4*)bet)[tid];
    u16x4 o;
    o[0] = f2b(dx * inv * G.x + Bt.x);
    o[1] = f2b(dy * inv * G.y + Bt.y);
    o[2] = f2b(dz * inv * G.z + Bt.z);
    o[3] = f2b(dw * inv * G.w + Bt.w);
    ((u16x4*)(yout + (size_t)row * 1024))[tid] = o;
}

// ---------------------------------------------------------------------------
// GEMM v9: C[M][N] = A[M][K](bf16) @ BT[N][K]^T(bf16) + epilogue
// BM x BN tile, BK in {32,64}, 4 waves (2x2). 3-stage LDS + counted vmcnt
// (T3/T4), ONE s_barrier per K-step.
// MODE 0: bias(3-way QKV select) + q-prescale, out bf16
// MODE 1: bias (b0) + residual (b1, fp32 [M][N]), out fp32
// MODE 2: bias + exact GELU, out bf16
// ---------------------------------------------------------------------------
template <int MODE, int BM, int BN, int BK>
__global__ __launch_bounds__(256, 2) void gemm_bf16(
    const u16* __restrict__ A, const u16* __restrict__ BT,
    const float* __restrict__ b0, const float* __restrict__ b1,
    const float* __restrict__ b2,
    void* __restrict__ outp, int M, int N, int K)
{
    constexpr int WM = BM / 2;
    constexpr int MI = WM / 16;           // m-fragments per wave
    constexpr int NI = BN / 32;           // n-fragments per wave
    constexpr int KS = BK / 32;           // k-subtiles per step (1 or 2)
    constexpr int AJ = BM * BK / 2048;    // A gload insts per wave per stage
    constexpr int BJ = BN * BK / 2048;    // B gload insts per wave per stage
    constexpr int LPS = AJ + BJ;          // loads per stage per wave
    constexpr int AELEM = BM * BK;
    constexpr int BELEM = BN * BK;
    constexpr int RSH = (BK == 64) ? 3 : 2;   // lane>>RSH = row within inst
    constexpr int RPI = 64 >> RSH;        // rows per gload inst
    __shared__ u16 Asm[3 * AELEM];
    __shared__ u16 Bsm[3 * BELEM];

    const int tid = threadIdx.x;
    const int lane = tid & 63, wid = tid >> 6;
    const int wm = wid >> 1, wn = wid & 1;
    const int g = lane >> 4, l16 = lane & 15;
    const int rkey = (BK == 64) ? (l16 & 7) : ((l16 >> 1) & 3);
    const int srow = lane >> RSH;
    const int sslot = (BK == 64) ? ((lane & 7) ^ (srow & 7))
                                 : ((lane & 3) ^ ((srow >> 1) & 3));

    const int nBN = N / BN;
    const int cpx = gridDim.x >> 3;
    const int wg = (blockIdx.x & 7) * cpx + (blockIdx.x >> 3);
    const int bm0 = (wg / nBN) * BM, bn0 = (wg % nBN) * BN;

    f32x4 acc[MI][NI] = {};

    const u16* aBase = A + (size_t)(bm0 + srow) * K + sslot * 8;
    const u16* bBase = BT + (size_t)(bn0 + srow) * K + sslot * 8;

    auto stage = [&](int kt, int buf) {
        u16* adst = Asm + buf * AELEM + lane * 8;
        u16* bdst = Bsm + buf * BELEM + lane * 8;
        #pragma unroll
        for (int j = 0; j < AJ; ++j) {
            const int ia = wid * AJ + j;
            __builtin_amdgcn_global_load_lds(AS1(aBase + (size_t)(ia * RPI) * K + kt),
                                             AS3(adst + ia * 512), 16, 0, 0);
        }
        #pragma unroll
        for (int j = 0; j < BJ; ++j) {
            const int ib = wid * BJ + j;
            __builtin_amdgcn_global_load_lds(AS1(bBase + (size_t)(ib * RPI) * K + kt),
                                             AS3(bdst + ib * 512), 16, 0, 0);
        }
    };

    const int nt = K / BK;
    stage(0, 0);
    stage(BK, 1);
    int cur = 0, pre = 2;

    for (int t = 0; t < nt; ++t) {
        if (t + 1 < nt) {
            if constexpr (LPS == 6)      asm volatile("s_waitcnt vmcnt(6)" ::: "memory");
            else if constexpr (LPS == 4) asm volatile("s_waitcnt vmcnt(4)" ::: "memory");
            else                         asm volatile("s_waitcnt vmcnt(3)" ::: "memory");
        } else {
            asm volatile("s_waitcnt vmcnt(0)" ::: "memory");
        }
        __builtin_amdgcn_s_barrier();
        __builtin_amdgcn_sched_barrier(0);

        const u16* asrc = Asm + cur * AELEM;
        const u16* bsrc = Bsm + cur * BELEM;
        bf16x8 af[KS][MI], bfr[KS][NI];
        #pragma unroll
        for (int ks = 0; ks < KS; ++ks) {
            #pragma unroll
            for (int mi = 0; mi < MI; ++mi) {
                const int r = wm * WM + mi * 16 + l16;
                const int slot = (ks * 4 + g) ^ rkey;
                af[ks][mi] = *(const bf16x8*)(asrc + r * BK + slot * 8);
            }
            #pragma unroll
            for (int ni = 0; ni < NI; ++ni) {
                const int c = wn * (BN / 2) + ni * 16 + l16;
                const int slot = (ks * 4 + g) ^ rkey;
                bfr[ks][ni] = *(const bf16x8*)(bsrc + c * BK + slot * 8);
            }
        }
        if (t + 2 < nt) stage((t + 2) * BK, pre);

        #pragma unroll
        for (int ks = 0; ks < KS; ++ks)
            #pragma unroll
            for (int mi = 0; mi < MI; ++mi)
                #pragma unroll
                for (int ni = 0; ni < NI; ++ni)
                    acc[mi][ni] = __builtin_amdgcn_mfma_f32_16x16x32_bf16(
                        af[ks][mi], bfr[ks][ni], acc[mi][ni], 0, 0, 0);

        pre = cur;
        cur = (cur == 2) ? 0 : cur + 1;
    }

    #pragma unroll
    for (int mi = 0; mi < MI; ++mi) {
        #pragma unroll
        for (int ni = 0; ni < NI; ++ni) {
            #pragma unroll
            for (int j = 0; j < 4; ++j) {
                const int m = bm0 + wm * WM + mi * 16 + g * 4 + j;
                const int n = bn0 + wn * (BN / 2) + ni * 16 + l16;
                float v = acc[mi][ni][j];
                if constexpr (MODE == 0) {
                    const float bias = (n < 1024) ? b0[n]
                                      : (n < 2048) ? b1[n - 1024] : b2[n - 2048];
                    float o = v + bias;
                    if (n < 1024) o *= QSCALE;     // pre-scale q for attn exp2
                    ((u16*)outp)[(size_t)m * N + n] = f2b(o);
                } else if constexpr (MODE == 1) {
                    ((float*)outp)[(size_t)m * N + n] =
                        v + b0[n] + b1[(size_t)m * N + n];
                } else {
                    ((u16*)outp)[(size_t)m * N + n] = f2b(gelu_exact(v + b0[n]));
                }
            }
        }
    }
}

// ---------------------------------------------------------------------------
// FF1 v3: faithful m201-style 8-phase schedule. 256x256 tile, 8 waves
// (2M x 4N, wave tile 128x64), K-tile 64, 2 LDS dbufs (128 KB, 1 block/CU).
// Per K-tile = 4 quadrant-phases, each {ds_read sub-tile || stage 1 half-tile
// -> barrier -> setprio(1) 16-MFMA setprio(0) -> barrier}. Half-tile stage
// schedule (race-audited; each overwritten region's last reader >=1 barrier
// earlier): q0:(t+1).A1->alt, q1:(t+1).B1->alt, q2:(t+2).B0->cur,
// q3:(t+2).A0->cur. Counted vmcnt(4) once per tile (never 0 until last).
// Quadrant order (0,0)(0,1)(1,1)(1,0): b01 frags live q0->q3, af reused.
// Epilogue: bias + exact GELU -> bf16. M=N=4096, K=1024 fixed.
// ---------------------------------------------------------------------------
__global__ __launch_bounds__(512, 1) void gemm_ff1(
    const u16* __restrict__ A, const u16* __restrict__ BT,
    const float* __restrict__ b0, u16* __restrict__ outp)
{
    __shared__ u16 Asm[2][256 * 64];   // 64 KB
    __shared__ u16 Bsm[2][256 * 64];   // 64 KB
    const int K = 1024, N = 4096;

    const int tid = threadIdx.x;
    const int lane = tid & 63, wid = tid >> 6;
    const int wr = wid >> 2, wc = wid & 3;        // 2M x 4N wave grid
    const int g = lane >> 4, l16 = lane & 15;
    const int srow8 = lane >> 3;                  // row within 8-row gload inst
    const int sslot = (lane & 7) ^ srow8;         // pre-swizzled source slot

    // XCD-bijective swizzle over 256 blocks; N-fastest within M-panel
    const int wg = (blockIdx.x & 7) * 32 + (blockIdx.x >> 3);
    const int bm0 = (wg >> 4) * 256, bn0 = (wg & 15) * 256;

    f32x4 acc[8][4] = {};

    // quarter: 0 = A rows 0-127, 1 = A rows 128-255, 2 = B rows 0-127,
    //          3 = B rows 128-255. Each stage = 1 half-tile (2 insts/thread).
    auto stage_half = [&](int th, int quarter) {
        const int kt = th * 64;
        const int rbase = (quarter & 1) * 128;
        const u16* src = (quarter < 2) ? (A + (size_t)bm0 * K)
                                       : (BT + (size_t)bn0 * K);
        u16* dst = (quarter < 2) ? Asm[th & 1] : Bsm[th & 1];
        #pragma unroll
        for (int i = 0; i < 2; ++i) {
            const int rr = rbase + (wid * 2 + i) * 8;
            __builtin_amdgcn_global_load_lds(
                AS1(src + (size_t)(rr + srow8) * K + kt + sslot * 8),
                AS3(dst + rr * 64 + lane * 8), 16, 0, 0);
        }
    };

    const int nt = 16;                  // K / 64
    // prologue: tile0 all 4 halves, then tile1.B0, tile1.A0
    stage_half(0, 0); stage_half(0, 1); stage_half(0, 2); stage_half(0, 3);
    stage_half(1, 2); stage_half(1, 0);
    asm volatile("s_waitcnt vmcnt(4)" ::: "memory");
    __builtin_amdgcn_s_barrier();
    __builtin_amdgcn_sched_barrier(0);

    for (int t = 0; t < nt; ++t) {
        const u16* as = Asm[t & 1];
        const u16* bs = Bsm[t & 1];
        bf16x8 af[2][4], b01[2][2], b23[2][2];

        // ===== q0: read A mi0-3 + B ni0-1; stage (t+1).A1; MFMA [0-3][0-1]
        #pragma unroll
        for (int ks = 0; ks < 2; ++ks) {
            #pragma unroll
            for (int mi = 0; mi < 4; ++mi) {
                const int r = wr * 128 + mi * 16 + l16;
                af[ks][mi] = *(const bf16x8*)(as + r * 64 + (((ks * 4 + g) ^ (r & 7)) << 3));
            }
            #pragma unroll
            for (int ni = 0; ni < 2; ++ni) {
                const int c = wc * 64 + ni * 16 + l16;
                b01[ks][ni] = *(const bf16x8*)(bs + c * 64 + (((ks * 4 + g) ^ (c & 7)) << 3));
            }
        }
        if (t + 1 < nt) stage_half(t + 1, 1);
        __builtin_amdgcn_s_barrier();
        __builtin_amdgcn_sched_barrier(0);
        __builtin_amdgcn_s_setprio(1);
        #pragma unroll
        for (int ks = 0; ks < 2; ++ks)
            #pragma unroll
            for (int mi = 0; mi < 4; ++mi)
                #pragma unroll
                for (int ni = 0; ni < 2; ++ni)
                    acc[mi][ni] = __builtin_amdgcn_mfma_f32_16x16x32_bf16(
                        af[ks][mi], b01[ks][ni], acc[mi][ni], 0, 0, 0);
        __builtin_amdgcn_s_setprio(0);
        __builtin_amdgcn_s_barrier();
        __builtin_amdgcn_sched_barrier(0);

        // ===== q1: read B ni2-3; stage (t+1).B1; MFMA [0-3][2-3]
        #pragma unroll
        for (int ks = 0; ks < 2; ++ks)
            #pragma unroll
            for (int ni = 0; ni < 2; ++ni) {
                const int c = wc * 64 + (ni + 2) * 16 + l16;
                b23[ks][ni] = *(const bf16x8*)(bs + c * 64 + (((ks * 4 + g) ^ (c & 7)) << 3));
            }
        if (t + 1 < nt) stage_half(t + 1, 3);
        __builtin_amdgcn_s_barrier();
        __builtin_amdgcn_sched_barrier(0);
        __builtin_amdgcn_s_setprio(1);
        #pragma unroll
        for (int ks = 0; ks < 2; ++ks)
            #pragma unroll
            for (int mi = 0; mi < 4; ++mi)
                #pragma unroll
                for (int ni = 0; ni < 2; ++ni)
                    acc[mi][ni + 2] = __builtin_amdgcn_mfma_f32_16x16x32_bf16(
                        af[ks][mi], b23[ks][ni], acc[mi][ni + 2], 0, 0, 0);
        __builtin_amdgcn_s_setprio(0);
        __builtin_amdgcn_s_barrier();
        __builtin_amdgcn_sched_barrier(0);

        // ===== q2: read A mi4-7 (reuse af storage); stage (t+2).B0; MFMA [4-7][2-3]
        #pragma unroll
        for (int ks = 0; ks < 2; ++ks)
            #pragma unroll
            for (int mi = 0; mi < 4; ++mi) {
                const int r = wr * 128 + (mi + 4) * 16 + l16;
                af[ks][mi] = *(const bf16x8*)(as + r * 64 + (((ks * 4 + g) ^ (r & 7)) << 3));
            }
        if (t + 2 < nt) stage_half(t + 2, 2);
        __builtin_amdgcn_s_barrier();
        __builtin_amdgcn_sched_barrier(0);
        __builtin_amdgcn_s_setprio(1);
        #pragma unroll
        for (int ks = 0; ks < 2; ++ks)
            #pragma unroll
            for (int mi = 0; mi < 4; ++mi)
                #pragma unroll
                for (int ni = 0; ni < 2; ++ni)
                    acc[mi + 4][ni + 2] = __builtin_amdgcn_mfma_f32_16x16x32_bf16(
                        af[ks][mi], b23[ks][ni], acc[mi + 4][ni + 2], 0, 0, 0);
        __builtin_amdgcn_s_setprio(0);
        __builtin_amdgcn_s_barrier();
        __builtin_amdgcn_sched_barrier(0);

        // ===== q3: no reads (af=mi4-7, b01 live); stage (t+2).A0; gate; MFMA [4-7][0-1]
        if (t + 2 < nt) stage_half(t + 2, 0);
        __builtin_amdgcn_s_barrier();
        __builtin_amdgcn_sched_barrier(0);
        __builtin_amdgcn_s_setprio(1);
        #pragma unroll
        for (int ks = 0; ks < 2; ++ks)
            #pragma unroll
            for (int mi = 0; mi < 4; ++mi)
                #pragma unroll
                for (int ni = 0; ni < 2; ++ni)
                    acc[mi + 4][ni] = __builtin_amdgcn_mfma_f32_16x16x32_bf16(
                        af[ks][mi], b01[ks][ni], acc[mi + 4][ni], 0, 0, 0);
        __builtin_amdgcn_s_setprio(0);
        // gate for next tile: its latest half was staged at (t,q1); stages
        // after it = (t,q2),(t,q3) = 4 loads -> vmcnt(4); 0 before last tile
        if (t + 1 < nt) {
            if (t + 1 == nt - 1) asm volatile("s_waitcnt vmcnt(0)" ::: "memory");
            else                 asm volatile("s_waitcnt vmcnt(4)" ::: "memory");
            __builtin_amdgcn_s_barrier();
            __builtin_amdgcn_sched_barrier(0);
        }
    }

    #pragma unroll
    for (int mi = 0; mi < 8; ++mi)
        #pragma unroll
        for (int ni = 0; ni < 4; ++ni)
            #pragma unroll
            for (int j = 0; j < 4; ++j) {
                const int m = bm0 + wr * 128 + mi * 16 + g * 4 + j;
                const int n = bn0 + wc * 64 + ni * 16 + l16;
                outp[(size_t)m * N + n] = f2b(gelu_exact(acc[mi][ni][j] + b0[n]));
            }
}

// ---------------------------------------------------------------------------
// Flash attention v3 (causal). qkv bf16 [4096][3072], q pre-scaled by QSCALE.
// Paired q-tiles, K/V double-buffer one-barrier-per-tile, m214 XOR swizzle,
// ones-MFMA row-sum, exp2 softmax, diagonal-only mask, T5 setprio.
// ---------------------------------------------------------------------------
__global__ __launch_bounds__(256) void attn_fwd(
    const u16* __restrict__ qkv, u16* __restrict__ outp)
{
    __shared__ u16 Ksm[2][64 * 64];
    __shared__ u16 Vsm[2][64 * 64];
    __shared__ u16 Psm[4][16 * 64];
    const int tid = threadIdx.x, lane = tid & 63, w = tid >> 6;
    const int lin = blockIdx.y * 8 + blockIdx.x;
    const int xq = (lin >> 3) & 7;
    const int bh = (((lin >> 6) & 7) << 3) | (lin & 7);
    const int b = bh >> 4, h = bh & 15;
    const int g = lane >> 4, l16 = lane & 15;
    const int skv = tid >> 4;
    const int sd4 = (tid & 15) * 4;

    const u16* kvb = qkv + (size_t)(b * 1024) * 3072 + 1024 + h * 64;

    bf16x8 vones;
    #pragma unroll
    for (int e = 0; e < 8; ++e) vones[e] = __builtin_bit_cast(__bf16, (u16)0x3F80);

    u16x4 kreg[4], vreg[4];
    auto issue = [&](int kv0) {
        const u16* kb = kvb + (size_t)kv0 * 3072;
        #pragma unroll
        for (int i = 0; i < 4; ++i)
            kreg[i] = *(const u16x4*)(kb + (size_t)(skv + 16 * i) * 3072 + sd4);
        #pragma unroll
        for (int i = 0; i < 4; ++i)
            vreg[i] = *(const u16x4*)(kb + (size_t)(4 * skv + i) * 3072 + 1024 + sd4);
    };
    auto stage_lds = [&](int buf) {
        #pragma unroll
        for (int i = 0; i < 4; ++i) {
            const int row = skv + 16 * i;
            *(u16x4*)(&Ksm[buf][row * 64 + (sd4 ^ ((row & 7) << 3))]) = kreg[i];
        }
        #pragma unroll
        for (int j = 0; j < 4; ++j) {
            u16x4 t;
            t[0] = vreg[0][j]; t[1] = vreg[1][j];
            t[2] = vreg[2][j]; t[3] = vreg[3][j];
            const int row = sd4 + j;
            *(u16x4*)(&Vsm[buf][row * 64 + ((4 * skv) ^ ((row & 7) << 3))]) = t;
        }
    };

    #pragma unroll
    for (int half = 0; half < 2; ++half) {
        const int qt = half ? (15 - xq) : xq;
        const int q0 = qt * 64;

        bf16x8 qf0, qf1;
        {
            const u16* qp = qkv + (size_t)(b * 1024 + q0 + w * 16 + l16) * 3072
                            + h * 64 + g * 8;
            qf0 = *(const bf16x8*)qp;
            qf1 = *(const bf16x8*)(qp + 32);
        }
        float m_run[4] = {-1e30f, -1e30f, -1e30f, -1e30f};
        float l_run[4] = {0.f, 0.f, 0.f, 0.f};
        f32x4 oacc[4] = {};

        issue(0);
        __syncthreads();
        stage_lds(0);
        if (qt > 0) issue(64);
        __syncthreads();
        int cur = 0;

        for (int kvt = 0; kvt <= qt; ++kvt) {
            f32x4 s[4];
            __builtin_amdgcn_s_setprio(1);
            #pragma unroll
            for (int t = 0; t < 4; ++t) {
                const int r = t * 16 + l16;
                const int sw = (r & 7) << 3;
                const bf16x8 kf0 = *(const bf16x8*)(&Ksm[cur][r * 64 + ((g * 8) ^ sw)]);
                const bf16x8 kf1 = *(const bf16x8*)(&Ksm[cur][r * 64 + (((g + 4) * 8) ^ sw)]);
                f32x4 z = {};
                z = __builtin_amdgcn_mfma_f32_16x16x32_bf16(qf0, kf0, z, 0, 0, 0);
                z = __builtin_amdgcn_mfma_f32_16x16x32_bf16(qf1, kf1, z, 0, 0, 0);
                s[t] = z;
            }
            __builtin_amdgcn_s_setprio(0);
            if (kvt == qt) {
                #pragma unroll
                for (int t = 0; t < 4; ++t)
                    #pragma unroll
                    for (int j = 0; j < 4; ++j) {
                        const int qrow = q0 + w * 16 + g * 4 + j;
                        const int kvc = q0 + t * 16 + l16;
                        if (kvc > qrow) s[t][j] = -1e30f;
                    }
            }
            float mx[4] = {-1e30f, -1e30f, -1e30f, -1e30f};
            #pragma unroll
            for (int t = 0; t < 4; ++t)
                #pragma unroll
                for (int j = 0; j < 4; ++j)
                    mx[j] = fmaxf(mx[j], s[t][j]);
            #pragma unroll
            for (int o = 1; o < 16; o <<= 1)
                #pragma unroll
                for (int j = 0; j < 4; ++j)
                    mx[j] = fmaxf(mx[j], __shfl_xor(mx[j], o, 16));
            float alpha[4];
            #pragma unroll
            for (int j = 0; j < 4; ++j) {
                const float mn = fmaxf(m_run[j], mx[j]);
                alpha[j] = __builtin_amdgcn_exp2f(m_run[j] - mn);
                m_run[j] = mn;
            }
            #pragma unroll
            for (int t = 0; t < 4; ++t)
                #pragma unroll
                for (int j = 0; j < 4; ++j)
                    s[t][j] = __builtin_amdgcn_exp2f(s[t][j] - m_run[j]);
            #pragma unroll
            for (int t = 0; t < 4; ++t)
                #pragma unroll
                for (int j = 0; j < 4; ++j) {
                    const int row = g * 4 + j;
                    Psm[w][row * 64 + ((t * 16 + l16) ^ ((row & 7) << 3))] = f2b(s[t][j]);
                }
            const int psw = (l16 & 7) << 3;
            const bf16x8 pf0 = *(const bf16x8*)(&Psm[w][l16 * 64 + ((g * 8) ^ psw)]);
            const bf16x8 pf1 = *(const bf16x8*)(&Psm[w][l16 * 64 + (((g + 4) * 8) ^ psw)]);
            f32x4 sum = {};
            sum = __builtin_amdgcn_mfma_f32_16x16x32_bf16(pf0, vones, sum, 0, 0, 0);
            sum = __builtin_amdgcn_mfma_f32_16x16x32_bf16(pf1, vones, sum, 0, 0, 0);
            #pragma unroll
            for (int j = 0; j < 4; ++j)
                l_run[j] = l_run[j] * alpha[j] + sum[j];
            #pragma unroll
            for (int dt = 0; dt < 4; ++dt)
                #pragma unroll
                for (int j = 0; j < 4; ++j)
                    oacc[dt][j] *= alpha[j];
            __builtin_amdgcn_s_setprio(1);
            #pragma unroll
            for (int dt = 0; dt < 4; ++dt) {
                const int rv = dt * 16 + l16;
                const int sw = (rv & 7) << 3;
                const bf16x8 vf0 = *(const bf16x8*)(&Vsm[cur][rv * 64 + ((g * 8) ^ sw)]);
                const bf16x8 vf1 = *(const bf16x8*)(&Vsm[cur][rv * 64 + (((g + 4) * 8) ^ sw)]);
                oacc[dt] = __builtin_amdgcn_mfma_f32_16x16x32_bf16(pf0, vf0, oacc[dt], 0, 0, 0);
                oacc[dt] = __builtin_amdgcn_mfma_f32_16x16x32_bf16(pf1, vf1, oacc[dt], 0, 0, 0);
            }
            __builtin_amdgcn_s_setprio(0);
            if (kvt < qt) {
                stage_lds(cur ^ 1);
                if (kvt + 2 <= qt) issue((kvt + 2) * 64);
                __syncthreads();
                cur ^= 1;
            }
        }
        #pragma unroll
        for (int j = 0; j < 4; ++j) l_run[j] = __builtin_amdgcn_rcpf(l_run[j]);
        #pragma unroll
        for (int dt = 0; dt < 4; ++dt)
            #pragma unroll
            for (int j = 0; j < 4; ++j) {
                const int m = b * 1024 + q0 + w * 16 + g * 4 + j;
                const int col = h * 64 + dt * 16 + l16;
                outp[(size_t)m * 1024 + col] = f2b(oacc[dt][j] * l_run[j]);
            }
    }
}

// ---------------------------------------------------------------------------
extern "C" void kernel_launch(void* const* d_in, const int* in_sizes, int n_in,
                              void* d_out, int out_size, void* d_ws, size_t ws_size,
                              hipStream_t stream)
{
    const float* x   = (const float*)d_in[0];
    const float* Wq  = (const float*)d_in[1];
    const float* bq  = (const float*)d_in[2];
    const float* Wk  = (const float*)d_in[3];
    const float* bk  = (const float*)d_in[4];
    const float* Wv  = (const float*)d_in[5];
    const float* bv  = (const float*)d_in[6];
    const float* Wp  = (const float*)d_in[7];
    const float* bp  = (const float*)d_in[8];
    const float* W1  = (const float*)d_in[9];
    const float* b1  = (const float*)d_in[10];
    const float* W2  = (const float*)d_in[11];
    const float* b2  = (const float*)d_in[12];
    const float* g1  = (const float*)d_in[13];
    const float* be1 = (const float*)d_in[14];
    const float* g2  = (const float*)d_in[15];
    const float* be2 = (const float*)d_in[16];

    char* ws = (char*)d_ws;
    const size_t MB = 1024 * 1024;
    u16*   ln_buf = (u16*)(ws);              //  8 MB [0,8)
    u16*   qkv    = (u16*)(ws + 8 * MB);     // 24 MB [8,32)
    u16*   attn_o = (u16*)(ws + 32 * MB);    //  8 MB [32,40)
    float* x1     = (float*)(ws + 40 * MB);  // 16 MB [40,56)
    u16*   hbuf   = (u16*)(ws + 56 * MB);    // 32 MB [56,88)
    u16*   wqkvT  = (u16*)(ws + 88 * MB);    //  6 MB [88,94)
    u16*   wpT    = (u16*)(ws + 94 * MB);    //  2 MB [94,96)
    u16*   w1T    = (u16*)(ws + 96 * MB);    //  8 MB [96,104)
    u16*   w2T    = (u16*)(ws + 104 * MB);   //  8 MB [104,112)

    transpose_w4<<<dim3(32, 32, 4), 256, 0, stream>>>(Wq, Wk, Wv, Wp, wqkvT, wpT);
    transpose_w<<<dim3(128, 32), 256, 0, stream>>>(W1, w1T, 1024, 4096);
    transpose_w<<<dim3(32, 128), 256, 0, stream>>>(W2, w2T, 4096, 1024);

    ln_bf16<<<4096, 256, 0, stream>>>(x, g1, be1, ln_buf);
    gemm_bf16<0, 128, 128, 32><<<768, 256, 0, stream>>>(   // QKV: 32x24, 3/CU
        ln_buf, wqkvT, bq, bk, bv, qkv, 4096, 3072, 1024);
    attn_fwd<<<dim3(8, 64), 256, 0, stream>>>(qkv, attn_o);
    gemm_bf16<1, 128, 64, 64><<<512, 256, 0, stream>>>(    // proj: BK=64
        attn_o, wpT, bp, x, nullptr, x1, 4096, 1024, 1024);
    ln_bf16<<<4096, 256, 0, stream>>>(x1, g2, be2, ln_buf);
    gemm_ff1<<<256, 512, 0, stream>>>(                     // FF1: 8-phase m201
        ln_buf, w1T, b1, hbuf);
    gemm_bf16<1, 128, 64, 64><<<512, 256, 0, stream>>>(    // FF2: BK=64
        hbuf, w2T, b2, x1, nullptr, (float*)d_out, 4096, 1024, 4096);
}

// Round 16
// 188.725 us; speedup vs baseline: 1.0231x; 1.0231x over previous
//
#include <hip/hip_runtime.h>
#include <hip/hip_bf16.h>

typedef __attribute__((ext_vector_type(8))) __bf16 bf16x8;
typedef __attribute__((ext_vector_type(4))) float f32x4;
typedef __attribute__((ext_vector_type(4))) unsigned short u16x4;
typedef unsigned short u16;

#define AS3(p) ((__attribute__((address_space(3))) void*)(p))
#define AS1(p) ((const __attribute__((address_space(1))) void*)(p))

// 0.125 (1/sqrt(64)) * log2(e): folded into q at QKV-GEMM epilogue so the
// attention softmax can use exp2 directly with no per-element scaling.
#define QSCALE 0.18033688011112042f

__device__ __forceinline__ u16 f2b(float f) {
    __hip_bfloat16 h = __float2bfloat16(f);
    return __builtin_bit_cast(u16, h);
}

// Exact-enough GELU: Abramowitz-Stegun 7.1.26 erf (max abs err 1.5e-7)
__device__ __forceinline__ float gelu_exact(float v) {
    const float z = v * 0.70710678118654752f;
    const float a = fabsf(z);
    const float t = __builtin_amdgcn_rcpf(1.0f + 0.3275911f * a);
    float p = 1.061405429f;
    p = p * t - 1.453152027f;
    p = p * t + 1.421413741f;
    p = p * t - 0.284496736f;
    p = p * t + 0.254829592f;
    p = p * t;
    float erfv = 1.0f - p * __expf(-a * a);
    erfv = copysignf(erfv, z);
    return 0.5f * v * (1.0f + erfv);
}

// ---------------------------------------------------------------------------
// Weight transpose: W [K][N] fp32 -> WT [N][K] bf16 (tiled, padded LDS)
// ---------------------------------------------------------------------------
__global__ __launch_bounds__(256) void transpose_w(
    const float* __restrict__ W, u16* __restrict__ WT, int K, int N)
{
    __shared__ u16 tile[32][33];
    const int tx = threadIdx.x & 31, ty = threadIdx.x >> 5;
    const int n0 = blockIdx.x * 32, k0 = blockIdx.y * 32;
    #pragma unroll
    for (int p = 0; p < 4; ++p)
        tile[ty + p * 8][tx] = f2b(W[(size_t)(k0 + ty + p * 8) * N + n0 + tx]);
    __syncthreads();
    #pragma unroll
    for (int p = 0; p < 4; ++p)
        WT[(size_t)(n0 + ty + p * 8) * K + k0 + tx] = tile[tx][ty + p * 8];
}

// Fused Q/K/V/P weight transpose (one launch, z picks the matrix)
__global__ __launch_bounds__(256) void transpose_w4(
    const float* __restrict__ W0, const float* __restrict__ W1,
    const float* __restrict__ W2, const float* __restrict__ W3,
    u16* __restrict__ WTqkv, u16* __restrict__ WTp)
{
    __shared__ u16 tile[32][33];
    const int z = blockIdx.z;
    const float* W = (z == 0) ? W0 : (z == 1) ? W1 : (z == 2) ? W2 : W3;
    u16* dst = (z == 3) ? WTp : WTqkv + (size_t)z * 1024 * 1024;
    const int tx = threadIdx.x & 31, ty = threadIdx.x >> 5;
    const int n0 = blockIdx.x * 32, k0 = blockIdx.y * 32;
    #pragma unroll
    for (int p = 0; p < 4; ++p)
        tile[ty + p * 8][tx] = f2b(W[(size_t)(k0 + ty + p * 8) * 1024 + n0 + tx]);
    __syncthreads();
    #pragma unroll
    for (int p = 0; p < 4; ++p)
        dst[(size_t)(n0 + ty + p * 8) * 1024 + k0 + tx] = tile[tx][ty + p * 8];
}

// ---------------------------------------------------------------------------
// LayerNorm: x fp32 [rows][1024] -> y bf16, one block per row
// ---------------------------------------------------------------------------
__global__ __launch_bounds__(256) void ln_bf16(
    const float* __restrict__ xin, const float* __restrict__ gam,
    const float* __restrict__ bet, u16* __restrict__ yout)
{
    __shared__ float red[8];
    const int row = blockIdx.x, tid = threadIdx.x;
    float4 v = ((const float4*)(xin + (size_t)row * 1024))[tid];
    float s = v.x + v.y + v.z + v.w;
    #pragma unroll
    for (int o = 32; o > 0; o >>= 1) s += __shfl_xor(s, o, 64);
    if ((tid & 63) == 0) red[tid >> 6] = s;
    __syncthreads();
    const float mu = (red[0] + red[1] + red[2] + red[3]) * (1.f / 1024.f);
    const float dx = v.x - mu, dy = v.y - mu, dz = v.z - mu, dw = v.w - mu;
    float sq = dx * dx + dy * dy + dz * dz + dw * dw;
    #pragma unroll
    for (int o = 32; o > 0; o >>= 1) sq += __shfl_xor(sq, o, 64);
    if ((tid & 63) == 0) red[4 + (tid >> 6)] = sq;
    __syncthreads();
    const float var = (red[4] + red[5] + red[6] + red[7]) * (1.f / 1024.f);
    const float inv = rsqrtf(var + 1e-5f);
    const float4 G = ((const float4*)gam)[tid];
    const float4 Bt = ((const float4*)bet)[tid];
    u16x4 o;
    o[0] = f2b(dx * inv * G.x + Bt.x);
    o[1] = f2b(dy * inv * G.y + Bt.y);
    o[2] = f2b(dz * inv * G.z + Bt.z);
    o[3] = f2b(dw * inv * G.w + Bt.w);
    ((u16x4*)(yout + (size_t)row * 1024))[tid] = o;
}

// ---------------------------------------------------------------------------
// GEMM v9: C[M][N] = A[M][K](bf16) @ BT[N][K]^T(bf16) + epilogue
// BM x BN tile, BK in {32,64}, 4 waves (2x2). 3-stage LDS + counted vmcnt
// (T3/T4), ONE s_barrier per K-step.
// MODE 0: bias(3-way QKV select) + q-prescale, out bf16
// MODE 1: bias (b0) + residual (b1, fp32 [M][N]), out fp32
// MODE 2: bias + exact GELU, out bf16
// ---------------------------------------------------------------------------
template <int MODE, int BM, int BN, int BK>
__global__ __launch_bounds__(256, 2) void gemm_bf16(
    const u16* __restrict__ A, const u16* __restrict__ BT,
    const float* __restrict__ b0, const float* __restrict__ b1,
    const float* __restrict__ b2,
    void* __restrict__ outp, int M, int N, int K)
{
    constexpr int WM = BM / 2;
    constexpr int MI = WM / 16;           // m-fragments per wave
    constexpr int NI = BN / 32;           // n-fragments per wave
    constexpr int KS = BK / 32;           // k-subtiles per step (1 or 2)
    constexpr int AJ = BM * BK / 2048;    // A gload insts per wave per stage
    constexpr int BJ = BN * BK / 2048;    // B gload insts per wave per stage
    constexpr int LPS = AJ + BJ;          // loads per stage per wave
    constexpr int AELEM = BM * BK;
    constexpr int BELEM = BN * BK;
    constexpr int RSH = (BK == 64) ? 3 : 2;   // lane>>RSH = row within inst
    constexpr int RPI = 64 >> RSH;        // rows per gload inst
    __shared__ u16 Asm[3 * AELEM];
    __shared__ u16 Bsm[3 * BELEM];

    const int tid = threadIdx.x;
    const int lane = tid & 63, wid = tid >> 6;
    const int wm = wid >> 1, wn = wid & 1;
    const int g = lane >> 4, l16 = lane & 15;
    const int rkey = (BK == 64) ? (l16 & 7) : ((l16 >> 1) & 3);
    const int srow = lane >> RSH;
    const int sslot = (BK == 64) ? ((lane & 7) ^ (srow & 7))
                                 : ((lane & 3) ^ ((srow >> 1) & 3));

    const int nBN = N / BN;
    const int cpx = gridDim.x >> 3;
    const int wg = (blockIdx.x & 7) * cpx + (blockIdx.x >> 3);
    const int bm0 = (wg / nBN) * BM, bn0 = (wg % nBN) * BN;

    f32x4 acc[MI][NI] = {};

    const u16* aBase = A + (size_t)(bm0 + srow) * K + sslot * 8;
    const u16* bBase = BT + (size_t)(bn0 + srow) * K + sslot * 8;

    auto stage = [&](int kt, int buf) {
        u16* adst = Asm + buf * AELEM + lane * 8;
        u16* bdst = Bsm + buf * BELEM + lane * 8;
        #pragma unroll
        for (int j = 0; j < AJ; ++j) {
            const int ia = wid * AJ + j;
            __builtin_amdgcn_global_load_lds(AS1(aBase + (size_t)(ia * RPI) * K + kt),
                                             AS3(adst + ia * 512), 16, 0, 0);
        }
        #pragma unroll
        for (int j = 0; j < BJ; ++j) {
            const int ib = wid * BJ + j;
            __builtin_amdgcn_global_load_lds(AS1(bBase + (size_t)(ib * RPI) * K + kt),
                                             AS3(bdst + ib * 512), 16, 0, 0);
        }
    };

    const int nt = K / BK;
    stage(0, 0);
    stage(BK, 1);
    int cur = 0, pre = 2;

    for (int t = 0; t < nt; ++t) {
        if (t + 1 < nt) {
            if constexpr (LPS == 6)      asm volatile("s_waitcnt vmcnt(6)" ::: "memory");
            else if constexpr (LPS == 4) asm volatile("s_waitcnt vmcnt(4)" ::: "memory");
            else                         asm volatile("s_waitcnt vmcnt(3)" ::: "memory");
        } else {
            asm volatile("s_waitcnt vmcnt(0)" ::: "memory");
        }
        __builtin_amdgcn_s_barrier();
        __builtin_amdgcn_sched_barrier(0);

        const u16* asrc = Asm + cur * AELEM;
        const u16* bsrc = Bsm + cur * BELEM;
        bf16x8 af[KS][MI], bfr[KS][NI];
        #pragma unroll
        for (int ks = 0; ks < KS; ++ks) {
            #pragma unroll
            for (int mi = 0; mi < MI; ++mi) {
                const int r = wm * WM + mi * 16 + l16;
                const int slot = (ks * 4 + g) ^ rkey;
                af[ks][mi] = *(const bf16x8*)(asrc + r * BK + slot * 8);
            }
            #pragma unroll
            for (int ni = 0; ni < NI; ++ni) {
                const int c = wn * (BN / 2) + ni * 16 + l16;
                const int slot = (ks * 4 + g) ^ rkey;
                bfr[ks][ni] = *(const bf16x8*)(bsrc + c * BK + slot * 8);
            }
        }
        if (t + 2 < nt) stage((t + 2) * BK, pre);

        #pragma unroll
        for (int ks = 0; ks < KS; ++ks)
            #pragma unroll
            for (int mi = 0; mi < MI; ++mi)
                #pragma unroll
                for (int ni = 0; ni < NI; ++ni)
                    acc[mi][ni] = __builtin_amdgcn_mfma_f32_16x16x32_bf16(
                        af[ks][mi], bfr[ks][ni], acc[mi][ni], 0, 0, 0);

        pre = cur;
        cur = (cur == 2) ? 0 : cur + 1;
    }

    #pragma unroll
    for (int mi = 0; mi < MI; ++mi) {
        #pragma unroll
        for (int ni = 0; ni < NI; ++ni) {
            #pragma unroll
            for (int j = 0; j < 4; ++j) {
                const int m = bm0 + wm * WM + mi * 16 + g * 4 + j;
                const int n = bn0 + wn * (BN / 2) + ni * 16 + l16;
                float v = acc[mi][ni][j];
                if constexpr (MODE == 0) {
                    const float bias = (n < 1024) ? b0[n]
                                      : (n < 2048) ? b1[n - 1024] : b2[n - 2048];
                    float o = v + bias;
                    if (n < 1024) o *= QSCALE;     // pre-scale q for attn exp2
                    ((u16*)outp)[(size_t)m * N + n] = f2b(o);
                } else if constexpr (MODE == 1) {
                    ((float*)outp)[(size_t)m * N + n] =
                        v + b0[n] + b1[(size_t)m * N + n];
                } else {
                    ((u16*)outp)[(size_t)m * N + n] = f2b(gelu_exact(v + b0[n]));
                }
            }
        }
    }
}

// ---------------------------------------------------------------------------
// FF1-dedicated GEMM (R12 proven version): 256x256 tile, 8 waves (2M x 4N,
// wave tile 128x64), BK=32, 4-stage LDS (128 KB, 1 block/CU), prefetch
// depth 3 with counted vmcnt(8). Single-phase K-step. (Phase-split variants
// regressed 4x: R8, R13, R15 — do not re-attempt.)
// Epilogue: bias + exact GELU -> bf16. M=4096, N=4096, K=1024 fixed.
// ---------------------------------------------------------------------------
__global__ __launch_bounds__(512, 2) void gemm_ff1(
    const u16* __restrict__ A, const u16* __restrict__ BT,
    const float* __restrict__ b0, u16* __restrict__ outp)
{
    constexpr int AELEM = 256 * 32;
    __shared__ u16 Asm[4 * AELEM];     // 64 KB
    __shared__ u16 Bsm[4 * AELEM];     // 64 KB
    const int K = 1024, N = 4096;

    const int tid = threadIdx.x;
    const int lane = tid & 63, wid = tid >> 6;
    const int wr = wid >> 2, wc = wid & 3;        // 2M x 4N wave grid
    const int g = lane >> 4, l16 = lane & 15;
    const int rkey = (l16 >> 1) & 3;
    const int srow = lane >> 2;                   // 16 rows per gload inst
    const int sslot = (lane & 3) ^ ((srow >> 1) & 3);

    // XCD-bijective swizzle over 256 blocks; N-fastest within M-panel
    const int wg = (blockIdx.x & 7) * 32 + (blockIdx.x >> 3);
    const int bm0 = (wg >> 4) * 256, bn0 = (wg & 15) * 256;

    f32x4 acc[8][4] = {};

    const u16* aBase = A + (size_t)(bm0 + srow) * K + sslot * 8;
    const u16* bBase = BT + (size_t)(bn0 + srow) * K + sslot * 8;

    auto stage = [&](int kt, int buf) {
        u16* adst = Asm + buf * AELEM + lane * 8;
        u16* bdst = Bsm + buf * AELEM + lane * 8;
        #pragma unroll
        for (int j = 0; j < 2; ++j) {
            const int ia = wid * 2 + j;           // 16 insts cover 256 rows
            __builtin_amdgcn_global_load_lds(AS1(aBase + (size_t)(ia * 16) * K + kt),
                                             AS3(adst + ia * 512), 16, 0, 0);
        }
        #pragma unroll
        for (int j = 0; j < 2; ++j) {
            const int ib = wid * 2 + j;
            __builtin_amdgcn_global_load_lds(AS1(bBase + (size_t)(ib * 16) * K + kt),
                                             AS3(bdst + ib * 512), 16, 0, 0);
        }
    };

    const int nt = 32;                  // K / 32
    stage(0, 0); stage(32, 1); stage(64, 2);
    int cur = 0;

    for (int t = 0; t < nt; ++t) {
        // gate tile t; allow stages t+1, t+2 (4 loads each) in flight
        if (t + 2 < nt)      asm volatile("s_waitcnt vmcnt(8)" ::: "memory");
        else if (t + 1 < nt) asm volatile("s_waitcnt vmcnt(4)" ::: "memory");
        else                 asm volatile("s_waitcnt vmcnt(0)" ::: "memory");
        __builtin_amdgcn_s_barrier();
        __builtin_amdgcn_sched_barrier(0);

        const u16* asrc = Asm + cur * AELEM;
        const u16* bsrc = Bsm + cur * AELEM;
        bf16x8 af[8], bfr[4];
        #pragma unroll
        for (int mi = 0; mi < 8; ++mi) {
            const int r = wr * 128 + mi * 16 + l16;
            af[mi] = *(const bf16x8*)(asrc + r * 32 + ((g ^ rkey) << 3));
        }
        #pragma unroll
        for (int ni = 0; ni < 4; ++ni) {
            const int c = wc * 64 + ni * 16 + l16;
            bfr[ni] = *(const bf16x8*)(bsrc + c * 32 + ((g ^ rkey) << 3));
        }
        if (t + 3 < nt) stage((t + 3) * 32, (t + 3) & 3);

        #pragma unroll
        for (int mi = 0; mi < 8; ++mi)
            #pragma unroll
            for (int ni = 0; ni < 4; ++ni)
                acc[mi][ni] = __builtin_amdgcn_mfma_f32_16x16x32_bf16(
                    af[mi], bfr[ni], acc[mi][ni], 0, 0, 0);

        cur = (cur + 1) & 3;
    }

    #pragma unroll
    for (int mi = 0; mi < 8; ++mi)
        #pragma unroll
        for (int ni = 0; ni < 4; ++ni)
            #pragma unroll
            for (int j = 0; j < 4; ++j) {
                const int m = bm0 + wr * 128 + mi * 16 + g * 4 + j;
                const int n = bn0 + wc * 64 + ni * 16 + l16;
                outp[(size_t)m * N + n] = f2b(gelu_exact(acc[mi][ni][j] + b0[n]));
            }
}

// ---------------------------------------------------------------------------
// Flash attention v4 (causal). qkv bf16 [4096][3072], q pre-scaled by QSCALE.
// Paired q-tiles, K/V double-buffer one-barrier-per-tile, m214 XOR swizzle,
// ones-MFMA row-sum, exp2 softmax, diagonal-only mask, T5 setprio.
// NEW: T13 defer-max — skip the O/l rescale when the tile max grows by <= 8
// (log2 domain: P <= 256, f32-safe; wave-uniform __all branch).
// ---------------------------------------------------------------------------
__global__ __launch_bounds__(256) void attn_fwd(
    const u16* __restrict__ qkv, u16* __restrict__ outp)
{
    __shared__ u16 Ksm[2][64 * 64];
    __shared__ u16 Vsm[2][64 * 64];
    __shared__ u16 Psm[4][16 * 64];
    const int tid = threadIdx.x, lane = tid & 63, w = tid >> 6;
    const int lin = blockIdx.y * 8 + blockIdx.x;
    const int xq = (lin >> 3) & 7;
    const int bh = (((lin >> 6) & 7) << 3) | (lin & 7);
    const int b = bh >> 4, h = bh & 15;
    const int g = lane >> 4, l16 = lane & 15;
    const int skv = tid >> 4;
    const int sd4 = (tid & 15) * 4;

    const u16* kvb = qkv + (size_t)(b * 1024) * 3072 + 1024 + h * 64;

    bf16x8 vones;
    #pragma unroll
    for (int e = 0; e < 8; ++e) vones[e] = __builtin_bit_cast(__bf16, (u16)0x3F80);

    u16x4 kreg[4], vreg[4];
    auto issue = [&](int kv0) {
        const u16* kb = kvb + (size_t)kv0 * 3072;
        #pragma unroll
        for (int i = 0; i < 4; ++i)
            kreg[i] = *(const u16x4*)(kb + (size_t)(skv + 16 * i) * 3072 + sd4);
        #pragma unroll
        for (int i = 0; i < 4; ++i)
            vreg[i] = *(const u16x4*)(kb + (size_t)(4 * skv + i) * 3072 + 1024 + sd4);
    };
    auto stage_lds = [&](int buf) {
        #pragma unroll
        for (int i = 0; i < 4; ++i) {
            const int row = skv + 16 * i;
            *(u16x4*)(&Ksm[buf][row * 64 + (sd4 ^ ((row & 7) << 3))]) = kreg[i];
        }
        #pragma unroll
        for (int j = 0; j < 4; ++j) {
            u16x4 t;
            t[0] = vreg[0][j]; t[1] = vreg[1][j];
            t[2] = vreg[2][j]; t[3] = vreg[3][j];
            const int row = sd4 + j;
            *(u16x4*)(&Vsm[buf][row * 64 + ((4 * skv) ^ ((row & 7) << 3))]) = t;
        }
    };

    #pragma unroll
    for (int half = 0; half < 2; ++half) {
        const int qt = half ? (15 - xq) : xq;
        const int q0 = qt * 64;

        bf16x8 qf0, qf1;
        {
            const u16* qp = qkv + (size_t)(b * 1024 + q0 + w * 16 + l16) * 3072
                            + h * 64 + g * 8;
            qf0 = *(const bf16x8*)qp;
            qf1 = *(const bf16x8*)(qp + 32);
        }
        float m_run[4] = {-1e30f, -1e30f, -1e30f, -1e30f};
        float l_run[4] = {0.f, 0.f, 0.f, 0.f};
        f32x4 oacc[4] = {};

        issue(0);
        __syncthreads();
        stage_lds(0);
        if (qt > 0) issue(64);
        __syncthreads();
        int cur = 0;

        for (int kvt = 0; kvt <= qt; ++kvt) {
            f32x4 s[4];
            __builtin_amdgcn_s_setprio(1);
            #pragma unroll
            for (int t = 0; t < 4; ++t) {
                const int r = t * 16 + l16;
                const int sw = (r & 7) << 3;
                const bf16x8 kf0 = *(const bf16x8*)(&Ksm[cur][r * 64 + ((g * 8) ^ sw)]);
                const bf16x8 kf1 = *(const bf16x8*)(&Ksm[cur][r * 64 + (((g + 4) * 8) ^ sw)]);
                f32x4 z = {};
                z = __builtin_amdgcn_mfma_f32_16x16x32_bf16(qf0, kf0, z, 0, 0, 0);
                z = __builtin_amdgcn_mfma_f32_16x16x32_bf16(qf1, kf1, z, 0, 0, 0);
                s[t] = z;
            }
            __builtin_amdgcn_s_setprio(0);
            if (kvt == qt) {
                #pragma unroll
                for (int t = 0; t < 4; ++t)
                    #pragma unroll
                    for (int j = 0; j < 4; ++j) {
                        const int qrow = q0 + w * 16 + g * 4 + j;
                        const int kvc = q0 + t * 16 + l16;
                        if (kvc > qrow) s[t][j] = -1e30f;
                    }
            }
            float mx[4] = {-1e30f, -1e30f, -1e30f, -1e30f};
            #pragma unroll
            for (int t = 0; t < 4; ++t)
                #pragma unroll
                for (int j = 0; j < 4; ++j)
                    mx[j] = fmaxf(mx[j], s[t][j]);
            #pragma unroll
            for (int o = 1; o < 16; o <<= 1)
                #pragma unroll
                for (int j = 0; j < 4; ++j)
                    mx[j] = fmaxf(mx[j], __shfl_xor(mx[j], o, 16));
            // T13 defer-max: skip rescale when growth <= 8 (P bounded by 2^8)
            const bool grow = (mx[0] > m_run[0] + 8.f) | (mx[1] > m_run[1] + 8.f)
                            | (mx[2] > m_run[2] + 8.f) | (mx[3] > m_run[3] + 8.f);
            if (__builtin_amdgcn_ballot_w64(grow) != 0ull) {
                #pragma unroll
                for (int j = 0; j < 4; ++j) {
                    const float mn = fmaxf(m_run[j], mx[j]);
                    const float alpha = __builtin_amdgcn_exp2f(m_run[j] - mn);
                    m_run[j] = mn;
                    l_run[j] *= alpha;
                    #pragma unroll
                    for (int dt = 0; dt < 4; ++dt)
                        oacc[dt][j] *= alpha;
                }
            }
            #pragma unroll
            for (int t = 0; t < 4; ++t)
                #pragma unroll
                for (int j = 0; j < 4; ++j)
                    s[t][j] = __builtin_amdgcn_exp2f(s[t][j] - m_run[j]);
            #pragma unroll
            for (int t = 0; t < 4; ++t)
                #pragma unroll
                for (int j = 0; j < 4; ++j) {
                    const int row = g * 4 + j;
                    Psm[w][row * 64 + ((t * 16 + l16) ^ ((row & 7) << 3))] = f2b(s[t][j]);
                }
            const int psw = (l16 & 7) << 3;
            const bf16x8 pf0 = *(const bf16x8*)(&Psm[w][l16 * 64 + ((g * 8) ^ psw)]);
            const bf16x8 pf1 = *(const bf16x8*)(&Psm[w][l16 * 64 + (((g + 4) * 8) ^ psw)]);
            f32x4 sum = {};
            sum = __builtin_amdgcn_mfma_f32_16x16x32_bf16(pf0, vones, sum, 0, 0, 0);
            sum = __builtin_amdgcn_mfma_f32_16x16x32_bf16(pf1, vones, sum, 0, 0, 0);
            #pragma unroll
            for (int j = 0; j < 4; ++j)
                l_run[j] += sum[j];
            __builtin_amdgcn_s_setprio(1);
            #pragma unroll
            for (int dt = 0; dt < 4; ++dt) {
                const int rv = dt * 16 + l16;
                const int sw = (rv & 7) << 3;
                const bf16x8 vf0 = *(const bf16x8*)(&Vsm[cur][rv * 64 + ((g * 8) ^ sw)]);
                const bf16x8 vf1 = *(const bf16x8*)(&Vsm[cur][rv * 64 + (((g + 4) * 8) ^ sw)]);
                oacc[dt] = __builtin_amdgcn_mfma_f32_16x16x32_bf16(pf0, vf0, oacc[dt], 0, 0, 0);
                oacc[dt] = __builtin_amdgcn_mfma_f32_16x16x32_bf16(pf1, vf1, oacc[dt], 0, 0, 0);
            }
            __builtin_amdgcn_s_setprio(0);
            if (kvt < qt) {
                stage_lds(cur ^ 1);
                if (kvt + 2 <= qt) issue((kvt + 2) * 64);
                __syncthreads();
                cur ^= 1;
            }
        }
        #pragma unroll
        for (int j = 0; j < 4; ++j) l_run[j] = __builtin_amdgcn_rcpf(l_run[j]);
        #pragma unroll
        for (int dt = 0; dt < 4; ++dt)
            #pragma unroll
            for (int j = 0; j < 4; ++j) {
                const int m = b * 1024 + q0 + w * 16 + g * 4 + j;
                const int col = h * 64 + dt * 16 + l16;
                outp[(size_t)m * 1024 + col] = f2b(oacc[dt][j] * l_run[j]);
            }
    }
}

// ---------------------------------------------------------------------------
extern "C" void kernel_launch(void* const* d_in, const int* in_sizes, int n_in,
                              void* d_out, int out_size, void* d_ws, size_t ws_size,
                              hipStream_t stream)
{
    const float* x   = (const float*)d_in[0];
    const float* Wq  = (const float*)d_in[1];
    const float* bq  = (const float*)d_in[2];
    const float* Wk  = (const float*)d_in[3];
    const float* bk  = (const float*)d_in[4];
    const float* Wv  = (const float*)d_in[5];
    const float* bv  = (const float*)d_in[6];
    const float* Wp  = (const float*)d_in[7];
    const float* bp  = (const float*)d_in[8];
    const float* W1  = (const float*)d_in[9];
    const float* b1  = (const float*)d_in[10];
    const float* W2  = (const float*)d_in[11];
    const float* b2  = (const float*)d_in[12];
    const float* g1  = (const float*)d_in[13];
    const float* be1 = (const float*)d_in[14];
    const float* g2  = (const float*)d_in[15];
    const float* be2 = (const float*)d_in[16];

    char* ws = (char*)d_ws;
    const size_t MB = 1024 * 1024;
    u16*   ln_buf = (u16*)(ws);              //  8 MB [0,8)
    u16*   qkv    = (u16*)(ws + 8 * MB);     // 24 MB [8,32)
    u16*   attn_o = (u16*)(ws + 32 * MB);    //  8 MB [32,40)
    float* x1     = (float*)(ws + 40 * MB);  // 16 MB [40,56)
    u16*   hbuf   = (u16*)(ws + 56 * MB);    // 32 MB [56,88)
    u16*   wqkvT  = (u16*)(ws + 88 * MB);    //  6 MB [88,94)
    u16*   wpT    = (u16*)(ws + 94 * MB);    //  2 MB [94,96)
    u16*   w1T    = (u16*)(ws + 96 * MB);    //  8 MB [96,104)
    u16*   w2T    = (u16*)(ws + 104 * MB);   //  8 MB [104,112)

    transpose_w4<<<dim3(32, 32, 4), 256, 0, stream>>>(Wq, Wk, Wv, Wp, wqkvT, wpT);
    transpose_w<<<dim3(128, 32), 256, 0, stream>>>(W1, w1T, 1024, 4096);
    transpose_w<<<dim3(32, 128), 256, 0, stream>>>(W2, w2T, 4096, 1024);

    ln_bf16<<<4096, 256, 0, stream>>>(x, g1, be1, ln_buf);
    gemm_bf16<0, 128, 128, 32><<<768, 256, 0, stream>>>(   // QKV: 32x24, 3/CU
        ln_buf, wqkvT, bq, bk, bv, qkv, 4096, 3072, 1024);
    attn_fwd<<<dim3(8, 64), 256, 0, stream>>>(qkv, attn_o);
    gemm_bf16<1, 128, 64, 64><<<512, 256, 0, stream>>>(    // proj: BK=64
        attn_o, wpT, bp, x, nullptr, x1, 4096, 1024, 1024);
    ln_bf16<<<4096, 256, 0, stream>>>(x1, g2, be2, ln_buf);
    gemm_ff1<<<256, 512, 0, stream>>>(                     // FF1: 256^2 (R12)
        ln_buf, w1T, b1, hbuf);
    gemm_bf16<1, 128, 64, 64><<<512, 256, 0, stream>>>(    // FF2: BK=64
        hbuf, w2T, b2, x1, nullptr, (float*)d_out, 4096, 1024, 4096);
}